// Round 8
// baseline (187.983 us; speedup 1.0000x reference)
//
#include <hip/hip_runtime.h>

// Problem constants
#define S_DIM 8192
#define K_DIM 1024
#define RO_DIM 4096
#define O_DIM 64
#define SO (S_DIM * O_DIM)
#define NSLICE 16  // N/256 partial slices

typedef __attribute__((ext_vector_type(8))) __bf16 bf16x8;
typedef __attribute__((ext_vector_type(4))) float floatx4;
typedef __attribute__((ext_vector_type(4))) unsigned short ushx4;
typedef __attribute__((ext_vector_type(8))) unsigned short ushx8;

__device__ inline unsigned short f2bf(float f) {
  unsigned u = __builtin_bit_cast(unsigned, f);
  u += 0x7fff + ((u >> 16) & 1);  // round-to-nearest-even
  return (unsigned short)(u >> 16);
}
__device__ inline float bf2f(unsigned short h) {
  unsigned u = ((unsigned)h) << 16;
  return __builtin_bit_cast(float, u);
}

// pure (non-volatile) so the scheduler can place/CSE freely; HW RNE rounding.
__device__ __forceinline__ unsigned cvtpk(float lo, float hi) {
  unsigned r;
  asm("v_cvt_pk_bf16_f32 %0, %1, %2" : "=v"(r) : "v"(lo), "v"(hi));
  return r;
}

// ---------------------------------------------------------------- 256x256 GEMM with fused fp32->bf16 staging
// R8 vs R6: the cast kernel is GONE. Staging loads fp32 X/W directly
// (4x global_load_dwordx4 / half-tile / thread), converts via v_cvt_pk_bf16_f32,
// and ds_write_b128's into the same linear XOR-swizzled LDS slots. Removes
// ~25-40us of cast work + 144MB traffic + one dispatch gap (non-GEMM time was
// a constant ~80us across R0-R7 while I tuned the 82us GEMM).
// Register-cliff discipline (we sit near the 256-reg 2-wave/SIMD boundary):
// each half-tile's LD is issued at the END of a phase (post-MFMA) and its WR
// happens at the TOP of the next phase (pre-MFMA) -> staging floats are dead
// during every MFMA cluster; peak-at-MFMA stays at R6 level.
//   q0: reads af03,bf01 | WR(ldA1 -> buf(kt+1) Ah1) | BAR | MFMA | LD(ldB0) | BAR
//   q1: reads bf23                                  | BAR | MFMA | LD(ldB1) | BAR
//   q2: reads af47      | WR(ldB0 -> buf(kt) Bh0)   | BAR | MFMA | LD(ldA0) | BAR
//   q3: WR(ldB1), WR(ldA0 -> buf(kt)) | MFMA | LD(ldA1) | lgkmcnt(0) | BAR
// WAR: every WR's slot had its last reader drained >=1 barrier earlier
// (Ah1: last read kt-1 q2; Bh0: q1; Bh1: q1; Ah0: q2 — all pre-q3 now, strictly
// cleaner than R6). Write->read visibility: first reader is >=4 barriers after
// the WR; the per-tile lgkmcnt(0) at q3 drains all ds_writes. No manual vmcnt:
// compiler data-dependency waits cover the reg-staged loads (1-phase latency
// window ~300-500cy covers L2/L3; ~10% HBM-miss stalls accepted).
// Kept from R6: quadrant phases, k-outermost MFMA, setprio, XOR k-chunk
// swizzle (pre-swizzled GLOBAL source, linear LDS dest, swizzled ds_read),
// XCD remap (XCD x owns bx in {2x,2x+1}), epilogue, reduce kernel.

template <int MB, int NB>
__device__ __forceinline__ void mfmaq(floatx4 (&acc)[8][4], const bf16x8 (&af)[4][2],
                                      const bf16x8 (&bf)[4][2]) {
  __builtin_amdgcn_s_setprio(1);
#pragma unroll
  for (int ks = 0; ks < 2; ++ks)
#pragma unroll
    for (int m = 0; m < 4; ++m)
#pragma unroll
      for (int n = 0; n < 2; ++n)
        acc[MB + m][NB + n] = __builtin_amdgcn_mfma_f32_16x16x32_bf16(
            af[m][ks], bf[NB + n][ks], acc[MB + m][NB + n], 0, 0, 0);
  __builtin_amdgcn_s_setprio(0);
}

struct ldset { float4 a, b, c, d; };  // 16 fp32 = one half-tile slice per thread

#define BAR() __builtin_amdgcn_s_barrier()

__global__ __launch_bounds__(512, 2) void gemm_kernel(const float* __restrict__ X,
                                                      const float* __restrict__ W,
                                                      const float* __restrict__ bias,
                                                      const float* __restrict__ lam,
                                                      unsigned short* __restrict__ partial) {
  __shared__ __align__(16) unsigned char smem[135168];  // 128KB buffers + 4KB lamsh
  unsigned short* sm = (unsigned short*)smem;
  float* lamsh = (float*)(smem + 131072);  // [256][4]

  const int t = threadIdx.x;
  const int lane = t & 63;
  const int w = t >> 6;
  const int wm = w >> 2;   // M half: rows wm*128..+127
  const int wn = w & 3;    // N quarter = rule index within block
  const int quad = lane >> 4;
  const int l16 = lane & 15;

  // XCD-locality remap: hw XCD = id%8. XCD x gets bx in {2x,2x+1}.
  int id = blockIdx.y * 16 + blockIdx.x;
  int x = id & 7;
  int j = id >> 3;               // 0..63
  const int bx = 2 * x + (j & 1);
  const int by = j >> 1;         // 0..31
  const int gm0 = by * 256;
  const int gn0 = bx * 256;

  // staging per-thread constants (gcc = chunk ^ (row&7) is thread-invariant)
  const int rowt = t >> 3;                       // 0..63
  const int gcc = (t & 7) ^ (rowt & 7);
  const size_t goffE = (size_t)rowt * K_DIM + (size_t)gcc * 8;  // ELEMENT offset
  const float* Asrc = X + (size_t)gm0 * K_DIM;
  const float* Bsrc = W + (size_t)gn0 * K_DIM;

  auto LDht = [&](ldset& h, const float* gb, int half, int ktile) {
    const float* p0 = gb + (size_t)(half * 128) * K_DIM + ktile * 64 + goffE;
    const float* p1 = p0 + (size_t)64 * K_DIM;
    h.a = *(const float4*)p0; h.b = *(const float4*)(p0 + 4);
    h.c = *(const float4*)p1; h.d = *(const float4*)(p1 + 4);
  };
  auto WRht = [&](const ldset& h, int slotOff) {
    uint4 w0, w1;
    w0.x = cvtpk(h.a.x, h.a.y); w0.y = cvtpk(h.a.z, h.a.w);
    w0.z = cvtpk(h.b.x, h.b.y); w0.w = cvtpk(h.b.z, h.b.w);
    w1.x = cvtpk(h.c.x, h.c.y); w1.y = cvtpk(h.c.z, h.c.w);
    w1.z = cvtpk(h.d.x, h.d.y); w1.w = cvtpk(h.d.z, h.d.w);
    *(uint4*)(sm + slotOff + t * 8) = w0;
    *(uint4*)(sm + slotOff + 4096 + t * 8) = w1;
  };

  // ---- prologue: stage tile0 full + tile1 {Bh0,Bh1,Ah0}; hold tile1-Ah1 in regs.
  {
    ldset u, v;
    LDht(u, Asrc, 0, 0); LDht(v, Asrc, 1, 0); WRht(u, 0);              WRht(v, 8192);
    LDht(u, Bsrc, 0, 0); LDht(v, Bsrc, 1, 0); WRht(u, 16384);          WRht(v, 24576);
    LDht(u, Bsrc, 0, 1); LDht(v, Bsrc, 1, 1); WRht(u, 32768 + 16384);  WRht(v, 32768 + 24576);
    LDht(u, Asrc, 0, 1); WRht(u, 32768 + 0);
  }
  ldset ldA1, ldB0, ldB1, ldA0;
  LDht(ldA1, Asrc, 1, 1);  // for WR at kt=0 q0 -> buf1 Ah1

  {
    int i = t;
    lamsh[i] = lam[(size_t)(gm0 + (i >> 2)) * 64 + bx * 4 + (i & 3)];
    i = t + 512;
    lamsh[i] = lam[(size_t)(gm0 + (i >> 2)) * 64 + bx * 4 + (i & 3)];
  }
  asm volatile("s_waitcnt lgkmcnt(0)" ::: "memory");
  BAR();

  // acc init = bias (exact fold)
  floatx4 acc[8][4];
#pragma unroll
  for (int ni = 0; ni < 4; ++ni) {
    float bv = bias[gn0 + wn * 64 + ni * 16 + l16];
#pragma unroll
    for (int mi = 0; mi < 8; ++mi) acc[mi][ni] = (floatx4){bv, bv, bv, bv};
  }

  const int cA0 = ((quad) ^ (l16 & 7)) * 8;        // k-chunk ks=0, swizzled
  const int cA1 = ((4 + quad) ^ (l16 & 7)) * 8;    // k-chunk ks=1, swizzled

  for (int kt = 0; kt < 16; ++kt) {
    const int b = kt & 1;
    const unsigned short* As = sm + b * 32768 + wm * 8192 + l16 * 64;
    const unsigned short* Bs = sm + b * 32768 + 16384 + wn * 4096 + l16 * 64;
    const int bufN = (b ^ 1) * 32768;  // tile kt+1's buffer
    const int bufC = b * 32768;        // tile kt+2's buffer (== current)

    bf16x8 afr[4][2], bfr[4][2];

    // ---- q0: reads af03 + bf01; WR(Ah1 of kt+1); MFMA; LD(Bh0 of kt+2)
#pragma unroll
    for (int m = 0; m < 4; ++m) {
      afr[m][0] = *(const bf16x8*)(As + m * 1024 + cA0);
      afr[m][1] = *(const bf16x8*)(As + m * 1024 + cA1);
    }
#pragma unroll
    for (int n = 0; n < 2; ++n) {
      bfr[n][0] = *(const bf16x8*)(Bs + n * 1024 + cA0);
      bfr[n][1] = *(const bf16x8*)(Bs + n * 1024 + cA1);
    }
    if (kt < 15) WRht(ldA1, bufN + 8192);
    BAR();
    mfmaq<0, 0>(acc, afr, bfr);
    if (kt < 14) LDht(ldB0, Bsrc, 0, kt + 2);
    BAR();

    // ---- q1: reads bf23; MFMA; LD(Bh1 of kt+2)
#pragma unroll
    for (int n = 2; n < 4; ++n) {
      bfr[n][0] = *(const bf16x8*)(Bs + n * 1024 + cA0);
      bfr[n][1] = *(const bf16x8*)(Bs + n * 1024 + cA1);
    }
    BAR();
    mfmaq<0, 2>(acc, afr, bfr);
    if (kt < 14) LDht(ldB1, Bsrc, 1, kt + 2);
    BAR();

    // ---- q2: reads af47; WR(Bh0 of kt+2); MFMA; LD(Ah0 of kt+2)
#pragma unroll
    for (int m = 0; m < 4; ++m) {
      afr[m][0] = *(const bf16x8*)(As + (4 + m) * 1024 + cA0);
      afr[m][1] = *(const bf16x8*)(As + (4 + m) * 1024 + cA1);
    }
    if (kt < 14) WRht(ldB0, bufC + 16384);
    BAR();
    mfmaq<4, 0>(acc, afr, bfr);
    if (kt < 14) LDht(ldA0, Asrc, 0, kt + 2);
    BAR();

    // ---- q3: WR(Bh1), WR(Ah0 of kt+2); MFMA; LD(Ah1 of kt+2); drain ds_writes
    if (kt < 14) {
      WRht(ldB1, bufC + 24576);
      WRht(ldA0, bufC + 0);
    }
    mfmaq<4, 2>(acc, afr, bfr);
    if (kt < 14) LDht(ldA1, Asrc, 1, kt + 2);
    asm volatile("s_waitcnt lgkmcnt(0)" ::: "memory");
    BAR();
  }

  // ---- epilogue: rule-weighted sigmoid -> LDS (bf16), 4-rule in-block reduce,
  // bf16 partial slice write (contention-free; reduce kernel finishes).
  __syncthreads();
  {
    unsigned short* yreg = sm + wn * 16384;  // [256][64], col-chunk ^= quad (banks)
#pragma unroll
    for (int mi = 0; mi < 8; ++mi) {
#pragma unroll
      for (int r = 0; r < 4; ++r) {
        int row = wm * 128 + mi * 16 + quad * 4 + r;
        float lamv = lamsh[row * 4 + wn];
#pragma unroll
        for (int ni = 0; ni < 4; ++ni) {
          float sg = 1.f / (1.f + __expf(-acc[mi][ni][r]));
          yreg[row * 64 + ((ni ^ quad) * 16) + l16] = f2bf(lamv * sg);
        }
      }
    }
  }
  __syncthreads();
  {
    unsigned short* pb = partial + (size_t)bx * SO + (size_t)gm0 * 64;
#pragma unroll
    for (int g = 0; g < 4; ++g) {
      int idx = g * 4096 + t * 8;  // lane-contiguous
      int row = idx >> 6;
      int c = idx & 63;
      int phys = row * 64 + ((((c >> 4) ^ ((row >> 2) & 3))) << 4) + (c & 15);
      float s[8];
#pragma unroll
      for (int jj = 0; jj < 8; ++jj) s[jj] = 0.f;
#pragma unroll
      for (int q = 0; q < 4; ++q) {
        ushx8 v = *(const ushx8*)(sm + q * 16384 + phys);
#pragma unroll
        for (int jj = 0; jj < 8; ++jj) s[jj] += bf2f(v[jj]);
      }
      ushx8 o;
#pragma unroll
      for (int jj = 0; jj < 8; ++jj) o[jj] = f2bf(s[jj]);
      *(ushx8*)(pb + idx) = o;
    }
  }
}

// ---------------------------------------------------------------- final reduce over 16 N-tiles
__global__ __launch_bounds__(256) void reduce_kernel(const unsigned short* __restrict__ partial,
                                                     float* __restrict__ Y) {
  int i4 = blockIdx.x * 256 + threadIdx.x;
  float s0 = 0.f, s1 = 0.f, s2 = 0.f, s3 = 0.f;
#pragma unroll
  for (int c = 0; c < NSLICE; ++c) {
    ushx4 v = ((const ushx4*)(partial + (size_t)c * SO))[i4];
    s0 += bf2f(v.x); s1 += bf2f(v.y); s2 += bf2f(v.z); s3 += bf2f(v.w);
  }
  ((float4*)Y)[i4] = (float4){s0, s1, s2, s3};
}

extern "C" void kernel_launch(void* const* d_in, const int* in_sizes, int n_in,
                              void* d_out, int out_size, void* d_ws, size_t ws_size,
                              hipStream_t stream) {
  const float* X = (const float*)d_in[0];     // [8192,1024]
  const float* W = (const float*)d_in[1];     // [4096,1024]
  const float* b = (const float*)d_in[2];     // [4096]
  const float* lam = (const float*)d_in[3];   // [8192,64]
  float* Y = (float*)d_out;                   // [8192,64]

  unsigned short* partial = (unsigned short*)d_ws;  // 16 slices x 1 MB

  dim3 g(RO_DIM / 256, S_DIM / 256);  // (16, 32) = 512 blocks, 512 threads
  gemm_kernel<<<g, 512, 0, stream>>>(X, W, b, lam, partial);

  reduce_kernel<<<SO / 1024, 256, 0, stream>>>(partial, Y);
}